// Round 1
// baseline (116.034 us; speedup 1.0000x reference)
//
#include <hip/hip_runtime.h>
#include <math.h>

#define N_  64
#define C_  256
#define S_  16
#define HW_ 3136      // 56*56
#define HW4_ 784      // HW/4

// Kernel 1: global average pool over H,W for each (n,c) row.
// One block of 256 threads per row; float4 vectorized loads.
__global__ __launch_bounds__(256) void se_pool(const float* __restrict__ x,
                                               float* __restrict__ s) {
    const int row = blockIdx.x;                  // n*C + c
    const float4* xr = reinterpret_cast<const float4*>(x + (size_t)row * HW_);
    float sum = 0.f;
    for (int i = threadIdx.x; i < HW4_; i += 256) {
        float4 v = xr[i];
        sum += (v.x + v.y) + (v.z + v.w);
    }
    // wave (64-lane) reduction
    #pragma unroll
    for (int off = 32; off; off >>= 1) sum += __shfl_down(sum, off, 64);
    __shared__ float partial[4];
    const int wave = threadIdx.x >> 6;
    const int lane = threadIdx.x & 63;
    if (lane == 0) partial[wave] = sum;
    __syncthreads();
    if (threadIdx.x == 0) {
        float t = (partial[0] + partial[1]) + (partial[2] + partial[3]);
        s[row] = t * (1.0f / (float)HW_);
    }
}

__device__ __forceinline__ float sigmoidf_(float v) {
    return 1.0f / (1.0f + expf(-v));
}

// Kernel 2: tiny MLP per image n: h = swish(w1 @ s + b1); g = sigmoid(w2 @ h + b2)
// One block of 256 threads per n.
__global__ __launch_bounds__(256) void se_mlp(const float* __restrict__ s,
                                              const float* __restrict__ w1,
                                              const float* __restrict__ b1,
                                              const float* __restrict__ w2,
                                              const float* __restrict__ b2,
                                              float* __restrict__ g) {
    const int n = blockIdx.x;
    const int t = threadIdx.x;       // 0..255
    __shared__ float s_sh[C_];
    __shared__ float h_sh[S_];
    s_sh[t] = s[n * C_ + t];
    __syncthreads();

    // h[j]: 16 outputs, each computed by a 16-thread group (contiguous lanes).
    const int j  = t >> 4;           // 0..15
    const int sl = t & 15;           // 0..15
    float p = 0.f;
    #pragma unroll
    for (int k = sl; k < C_; k += 16) p += s_sh[k] * w1[j * C_ + k];
    // reduce within the 16-lane group (lanes contiguous inside the wave)
    #pragma unroll
    for (int m = 8; m; m >>= 1) p += __shfl_xor(p, m, 64);
    if (sl == 0) {
        float hv = p + b1[j];
        h_sh[j] = hv * sigmoidf_(hv);     // swish
    }
    __syncthreads();

    // g[c]: each thread owns one channel, dot over S_=16.
    float acc = b2[t];
    #pragma unroll
    for (int k = 0; k < S_; ++k) acc += h_sh[k] * w2[t * S_ + k];
    g[n * C_ + t] = sigmoidf_(acc);
}

// Kernel 3: out = x * g[n,c], broadcast over spatial. float4 grid-stride.
__global__ __launch_bounds__(256) void se_scale(const float* __restrict__ x,
                                                const float* __restrict__ g,
                                                float* __restrict__ out) {
    const int total4 = N_ * C_ * HW4_;           // 12,845,056 float4 units
    const float4* x4 = reinterpret_cast<const float4*>(x);
    float4* o4 = reinterpret_cast<float4*>(out);
    for (int i = blockIdx.x * 256 + threadIdx.x; i < total4; i += gridDim.x * 256) {
        const int row = i / HW4_;                // n*C + c  (magic-mul division)
        const float gv = g[row];
        float4 v = x4[i];
        v.x *= gv; v.y *= gv; v.z *= gv; v.w *= gv;
        o4[i] = v;
    }
}

extern "C" void kernel_launch(void* const* d_in, const int* in_sizes, int n_in,
                              void* d_out, int out_size, void* d_ws, size_t ws_size,
                              hipStream_t stream) {
    const float* x  = (const float*)d_in[0];
    const float* w1 = (const float*)d_in[1];
    const float* b1 = (const float*)d_in[2];
    const float* w2 = (const float*)d_in[3];
    const float* b2 = (const float*)d_in[4];
    float* out = (float*)d_out;

    float* s = (float*)d_ws;          // N*C floats = 64 KiB
    float* g = s + N_ * C_;           // N*C floats = 64 KiB

    se_pool<<<N_ * C_, 256, 0, stream>>>(x, s);
    se_mlp<<<N_, 256, 0, stream>>>(s, w1, b1, w2, b2, g);
    se_scale<<<2048, 256, 0, stream>>>(x, g, out);
}

// Round 3
// 99.562 us; speedup vs baseline: 1.1654x; 1.1654x over previous
//
#include <hip/hip_runtime.h>
#include <math.h>

#define N_  64
#define C_  256
#define S_  16
#define HW_ 3136      // 56*56
#define HW4_ 784      // HW/4

typedef float f32x4 __attribute__((ext_vector_type(4)));

// Kernel 1: global average pool over H,W for each (n,c) row.
// One block of 256 threads per row; float4 vectorized loads.
// Normal (caching) loads on purpose: this pass populates L3 with x so the
// scale pass can hit it.
__global__ __launch_bounds__(256) void se_pool(const float* __restrict__ x,
                                               float* __restrict__ s) {
    const int row = blockIdx.x;                  // n*C + c
    const f32x4* xr = reinterpret_cast<const f32x4*>(x + (size_t)row * HW_);
    float sum = 0.f;
    for (int i = threadIdx.x; i < HW4_; i += 256) {
        f32x4 v = xr[i];
        sum += (v.x + v.y) + (v.z + v.w);
    }
    // wave (64-lane) reduction
    #pragma unroll
    for (int off = 32; off; off >>= 1) sum += __shfl_down(sum, off, 64);
    __shared__ float partial[4];
    const int wave = threadIdx.x >> 6;
    const int lane = threadIdx.x & 63;
    if (lane == 0) partial[wave] = sum;
    __syncthreads();
    if (threadIdx.x == 0) {
        float t = (partial[0] + partial[1]) + (partial[2] + partial[3]);
        s[row] = t * (1.0f / (float)HW_);
    }
}

__device__ __forceinline__ float sigmoidf_(float v) {
    return 1.0f / (1.0f + expf(-v));
}

// Kernel 2: tiny MLP per image n: h = swish(w1 @ s + b1); g = sigmoid(w2 @ h + b2)
// One block of 256 threads per n.
__global__ __launch_bounds__(256) void se_mlp(const float* __restrict__ s,
                                              const float* __restrict__ w1,
                                              const float* __restrict__ b1,
                                              const float* __restrict__ w2,
                                              const float* __restrict__ b2,
                                              float* __restrict__ g) {
    const int n = blockIdx.x;
    const int t = threadIdx.x;       // 0..255
    __shared__ float s_sh[C_];
    __shared__ float h_sh[S_];
    s_sh[t] = s[n * C_ + t];
    __syncthreads();

    // h[j]: 16 outputs, each computed by a 16-thread group (contiguous lanes).
    const int j  = t >> 4;           // 0..15
    const int sl = t & 15;           // 0..15
    float p = 0.f;
    #pragma unroll
    for (int k = sl; k < C_; k += 16) p += s_sh[k] * w1[j * C_ + k];
    // reduce within the 16-lane group (lanes contiguous inside the wave)
    #pragma unroll
    for (int m = 8; m; m >>= 1) p += __shfl_xor(p, m, 64);
    if (sl == 0) {
        float hv = p + b1[j];
        h_sh[j] = hv * sigmoidf_(hv);     // swish
    }
    __syncthreads();

    // g[c]: each thread owns one channel, dot over S_=16.
    float acc = b2[t];
    #pragma unroll
    for (int k = 0; k < S_; ++k) acc += h_sh[k] * w2[t * S_ + k];
    g[n * C_ + t] = sigmoidf_(acc);
}

// Kernel 3: out[row, :] = x[row, :] * g[row]. One block per (n,c) row.
// g[row] is wave-uniform; x-read should hit L3 (loaded by se_pool moments
// earlier); out is written NON-TEMPORAL so the write stream doesn't evict x
// from the Infinity Cache.
__global__ __launch_bounds__(256) void se_scale(const float* __restrict__ x,
                                                const float* __restrict__ g,
                                                float* __restrict__ out) {
    const int row = blockIdx.x;                  // n*C + c
    const float gv = g[row];
    const f32x4* xr = reinterpret_cast<const f32x4*>(x + (size_t)row * HW_);
    f32x4* orow = reinterpret_cast<f32x4*>(out + (size_t)row * HW_);
    for (int i = threadIdx.x; i < HW4_; i += 256) {
        f32x4 v = xr[i];
        v *= gv;
        __builtin_nontemporal_store(v, &orow[i]);
    }
}

extern "C" void kernel_launch(void* const* d_in, const int* in_sizes, int n_in,
                              void* d_out, int out_size, void* d_ws, size_t ws_size,
                              hipStream_t stream) {
    const float* x  = (const float*)d_in[0];
    const float* w1 = (const float*)d_in[1];
    const float* b1 = (const float*)d_in[2];
    const float* w2 = (const float*)d_in[3];
    const float* b2 = (const float*)d_in[4];
    float* out = (float*)d_out;

    float* s = (float*)d_ws;          // N*C floats = 64 KiB
    float* g = s + N_ * C_;           // N*C floats = 64 KiB

    se_pool<<<N_ * C_, 256, 0, stream>>>(x, s);
    se_mlp<<<N_, 256, 0, stream>>>(s, w1, b1, w2, b2, g);
    se_scale<<<N_ * C_, 256, 0, stream>>>(x, g, out);
}